// Round 1
// baseline (189.450 us; speedup 1.0000x reference)
//
#include <hip/hip_runtime.h>

#define T_DATA 20000
#define S_NO   128
#define T_HIST 100
#define NELEM  (T_DATA * S_NO)   // 2,560,000

__device__ __forceinline__ float sigm(float v) {
    return 1.0f / (1.0f + __expf(-v));
}

// ---------------------------------------------------------------------------
// K1: prep — transpose C, build ancestor kernel (transposed [j][s]) and
// history kernel ([s][j]); set flag = any(K_hist != 0).
// ---------------------------------------------------------------------------
__global__ void k1_prep(const float* __restrict__ C,
                        const float* __restrict__ K_spike,
                        const float* __restrict__ tau_spike,
                        const float* __restrict__ delta_spike,
                        const float* __restrict__ tau_hist,
                        const float* __restrict__ K_hist,
                        const float* __restrict__ delta_hist,
                        float* __restrict__ Ct,
                        float* __restrict__ anc_kT,
                        float* __restrict__ hist_k,
                        int* __restrict__ flag) {
    const int tid = threadIdx.x;          // 256 threads, 1 block
    // transpose C: Ct[k][s] = C[s][k]
    for (int q = tid; q < S_NO * S_NO; q += 256) {
        int s = q >> 7, k = q & 127;
        Ct[k * S_NO + s] = C[q];
    }
    const int s    = tid & 127;
    const int half = tid >> 7;            // 0 or 1 -> j chunks of 50
    // ancestor (spike) kernel, stored transposed: anc_kT[j*128 + s]
    {
        float d  = delta_spike[s];
        float i0 = __expf(-tau_spike[0]);
        float i1 = __expf(-tau_spike[1]);
        float i2 = __expf(-tau_spike[2]);
        float k0 = K_spike[s * 3 + 0], k1 = K_spike[s * 3 + 1], k2 = K_spike[s * 3 + 2];
        for (int j = half * 50; j < half * 50 + 50; ++j) {
            float t  = fmaxf((float)j - d, 0.0f);
            float x0 = t * i0, x1 = t * i1, x2 = t * i2;
            anc_kT[j * S_NO + s] =
                k0 * x0 * __expf(-x0) + k1 * x1 * __expf(-x1) + k2 * x2 * __expf(-x2);
        }
    }
    // history kernel, stored row-major per subunit: hist_k[s*100 + j]
    {
        float d  = delta_hist[s];
        float i0 = __expf(-tau_hist[0]);
        float i1 = __expf(-tau_hist[1]);
        float i2 = __expf(-tau_hist[2]);
        float k0 = K_hist[s * 3 + 0], k1 = K_hist[s * 3 + 1], k2 = K_hist[s * 3 + 2];
        for (int j = half * 50; j < half * 50 + 50; ++j) {
            float t  = fmaxf((float)j - d, 0.0f);
            float x0 = t * i0, x1 = t * i1, x2 = t * i2;
            hist_k[s * T_HIST + j] =
                k0 * x0 * __expf(-x0) + k1 * x1 * __expf(-x1) + k2 * x2 * __expf(-x2);
        }
    }
    if (tid == 0) *flag = 0;
    __syncthreads();
    if (tid < 128) {
        if (K_hist[s * 3] != 0.0f || K_hist[s * 3 + 1] != 0.0f || K_hist[s * 3 + 2] != 0.0f)
            atomicOr(flag, 1);
    }
}

// ---------------------------------------------------------------------------
// K2: dual GEMM  A = Z @ C^T, R = Y @ C^T   (each (20000,128)x(128,128))
// 16 timesteps per block, 256 threads: thread (s, th) computes 8 t-rows.
// ---------------------------------------------------------------------------
__global__ void __launch_bounds__(256) k2_gemm(const float* __restrict__ Z,
                                               const float* __restrict__ Y,
                                               const float* __restrict__ Ct,
                                               float* __restrict__ A,
                                               float* __restrict__ R) {
    __shared__ float Zt[16][128];
    __shared__ float Yt[16][128];
    const int t0  = blockIdx.x * 16;
    const int tid = threadIdx.x;
    // stage 16x128 tiles (contiguous in global)
    {
        const float4* Zg = (const float4*)(Z + t0 * S_NO);
        const float4* Yg = (const float4*)(Y + t0 * S_NO);
        float4* Zl = (float4*)&Zt[0][0];
        float4* Yl = (float4*)&Yt[0][0];
        for (int q = tid; q < 512; q += 256) { Zl[q] = Zg[q]; Yl[q] = Yg[q]; }
    }
    __syncthreads();
    const int s  = tid & 127;
    const int tb = (tid >> 7) * 8;
    float accA[8] = {0, 0, 0, 0, 0, 0, 0, 0};
    float accR[8] = {0, 0, 0, 0, 0, 0, 0, 0};
    for (int k4 = 0; k4 < 32; ++k4) {
        const float c0 = Ct[(k4 * 4 + 0) * S_NO + s];
        const float c1 = Ct[(k4 * 4 + 1) * S_NO + s];
        const float c2 = Ct[(k4 * 4 + 2) * S_NO + s];
        const float c3 = Ct[(k4 * 4 + 3) * S_NO + s];
#pragma unroll
        for (int i = 0; i < 8; ++i) {
            float4 z = *(const float4*)&Zt[tb + i][k4 * 4];
            accA[i] = fmaf(c0, z.x, fmaf(c1, z.y, fmaf(c2, z.z, fmaf(c3, z.w, accA[i]))));
            float4 y = *(const float4*)&Yt[tb + i][k4 * 4];
            accR[i] = fmaf(c0, y.x, fmaf(c1, y.y, fmaf(c2, y.z, fmaf(c3, y.w, accR[i]))));
        }
    }
#pragma unroll
    for (int i = 0; i < 8; ++i) {
        A[(t0 + tb + i) * S_NO + s] = accA[i];
        R[(t0 + tb + i) * S_NO + s] = accR[i];
    }
}

// ---------------------------------------------------------------------------
// K3: 100-tap causal conv along time:
//   F[t,s] = sum_{j=0..99} A[t-1-j, s] * anc_k[s][j]   (A index <0 -> 0)
// Block: 40 timesteps x 64 subunits. Rolling 10-deep register window ->
// 1 LDS read per 10 FMA.
// ---------------------------------------------------------------------------
__global__ void __launch_bounds__(256) k3_conv(const float* __restrict__ A,
                                               const float* __restrict__ anc_kT,
                                               float* __restrict__ F) {
    __shared__ float Al[140 * 64];
    const int tstart = blockIdx.x * 40;
    const int shalf  = blockIdx.y;
    const int tid    = threadIdx.x;
    // stage A rows u = tstart-100 .. tstart+39 (zero for u<0)
    for (int q = tid; q < 140 * 16; q += 256) {
        const int row = q >> 4, c4 = q & 15;
        const int u  = tstart - 100 + row;
        float4 v = make_float4(0.f, 0.f, 0.f, 0.f);
        if (u >= 0) v = *(const float4*)&A[u * S_NO + shalf * 64 + c4 * 4];
        *(float4*)&Al[row * 64 + c4 * 4] = v;
    }
    __syncthreads();
    const int sl    = tid & 63;
    const int tg    = tid >> 6;         // 0..3, 10 timesteps each
    const int sg    = shalf * 64 + sl;
    const int rbase = tg * 10;
    float acc[10] = {0, 0, 0, 0, 0, 0, 0, 0, 0, 0};
    float W[10];
    // at j=0: V_i = A[T0+i-1] lives in LDS row rbase+99+i
#pragma unroll
    for (int i = 0; i < 10; ++i) W[i] = Al[(rbase + 99 + i) * 64 + sl];
#pragma unroll
    for (int j = 0; j < 100; ++j) {
        const float kv = anc_kT[j * S_NO + sg];
#pragma unroll
        for (int i = 0; i < 10; ++i)
            acc[i] = fmaf(W[(((i - j) % 10) + 10) % 10], kv, acc[i]);
        if (j < 99)  // load V'_0 = A[T0-2-j] for next iteration
            W[(10 - ((j + 1) % 10)) % 10] = Al[(rbase + 98 - j) * 64 + sl];
    }
    const int T0 = tstart + rbase;
#pragma unroll
    for (int i = 0; i < 10; ++i) F[(T0 + i) * S_NO + sg] = acc[i];
}

// ---------------------------------------------------------------------------
// K4: final nonlinear map.
//  fast path (hist kernel == 0): fully parallel elementwise, float4.
//  slow path: exact sequential scan, one block (one wave) per subunit.
//  In both: reads R from out1 / F from out3 then overwrites the same element.
// ---------------------------------------------------------------------------
__global__ void __launch_bounds__(256) k4_final(const float* __restrict__ S_conv,
                                                const float* __restrict__ noise,
                                                const float* __restrict__ W_sub,
                                                const float* __restrict__ theta_syn,
                                                const float* __restrict__ theta_spike,
                                                const float* __restrict__ W_spike,
                                                const float* __restrict__ hist_k,
                                                const int* __restrict__ flag,
                                                float* out0, float* out1,
                                                float* out2, float* out3) {
    __shared__ float zr[128];
    if (*flag == 0) {
        // ---- fast path: fh == 0 everywhere ----
        const int n4 = blockIdx.x * blockDim.x + threadIdx.x;   // 0..639999
        if (n4 >= NELEM / 4) return;
        const int r = n4 & 31;   // float4 index within a 128-wide row
        const float4 sc = ((const float4*)S_conv)[n4];
        const float4 rr = ((const float4*)out1)[n4];
        const float4 ff = ((const float4*)out3)[n4];
        const float4 nz = ((const float4*)noise)[n4];
        const float4 ts = ((const float4*)theta_syn)[r];
        const float4 wu = ((const float4*)W_sub)[r];
        const float4 wk = ((const float4*)W_spike)[r];
        const float4 tk = ((const float4*)theta_spike)[r];
        float4 y, z, dn;
        {
            float x = sigm(sc.x + ts.x + rr.x + ff.x);
            y.x = x * wu.x; dn.x = fmaf(x, wk.x, tk.x); z.x = sigm(dn.x + nz.x);
        }
        {
            float x = sigm(sc.y + ts.y + rr.y + ff.y);
            y.y = x * wu.y; dn.y = fmaf(x, wk.y, tk.y); z.y = sigm(dn.y + nz.y);
        }
        {
            float x = sigm(sc.z + ts.z + rr.z + ff.z);
            y.z = x * wu.z; dn.z = fmaf(x, wk.z, tk.z); z.z = sigm(dn.z + nz.z);
        }
        {
            float x = sigm(sc.w + ts.w + rr.w + ff.w);
            y.w = x * wu.w; dn.w = fmaf(x, wk.w, tk.w); z.w = sigm(dn.w + nz.w);
        }
        ((float4*)out0)[n4] = y;
        ((float4*)out1)[n4] = z;
        ((float4*)out2)[n4] = dn;
        ((float4*)out3)[n4] = dn;
    } else {
        // ---- slow path: exact sequential recurrence, one wave per subunit ----
        const int s = blockIdx.x;
        if (s >= S_NO || threadIdx.x >= 64) return;
        const int l = threadIdx.x;
        zr[l] = 0.0f; zr[l + 64] = 0.0f;   // single wave: no barrier needed
        const float hk0 = (l < T_HIST) ? hist_k[s * T_HIST + l] : 0.0f;
        const float hk1 = (l + 64 < T_HIST) ? hist_k[s * T_HIST + l + 64] : 0.0f;
        const float tsy = theta_syn[s], wsub = W_sub[s];
        const float wsp = W_spike[s],  tsp  = theta_spike[s];
        for (int t = 0; t < T_DATA; ++t) {
            float fh = hk0 * zr[(t - 1 - l) & 127];
            fh = fmaf(hk1, zr[(t - 65 - l) & 127], fh);
#pragma unroll
            for (int m = 1; m < 64; m <<= 1) fh += __shfl_xor(fh, m, 64);
            const int n = t * S_NO + s;
            const float basev = S_conv[n] + tsy + out1[n] + out3[n];
            const float x  = sigm(basev + fh);
            const float dn = fmaf(x, wsp, tsp);
            const float z  = sigm(dn + noise[n]);
            if (l == 0) {
                out0[n] = x * wsub;
                out1[n] = z;
                out2[n] = dn;
                out3[n] = dn;
                zr[t & 127] = z;
            }
        }
    }
}

// ---------------------------------------------------------------------------
extern "C" void kernel_launch(void* const* d_in, const int* in_sizes, int n_in,
                              void* d_out, int out_size, void* d_ws, size_t ws_size,
                              hipStream_t stream) {
    const float* S_conv  = (const float*)d_in[0];
    const float* Y_anc   = (const float*)d_in[1];
    const float* Z_anc   = (const float*)d_in[2];
    const float* noise   = (const float*)d_in[3];
    const float* C_den   = (const float*)d_in[4];
    const float* W_sub   = (const float*)d_in[5];
    const float* th_syn  = (const float*)d_in[6];
    const float* K_spk   = (const float*)d_in[7];
    const float* tau_spk = (const float*)d_in[8];
    const float* dl_spk  = (const float*)d_in[9];
    const float* th_spk  = (const float*)d_in[10];
    const float* W_spk   = (const float*)d_in[11];
    const float* tau_h   = (const float*)d_in[12];
    const float* K_h     = (const float*)d_in[13];
    const float* dl_h    = (const float*)d_in[14];

    float* out  = (float*)d_out;
    float* out0 = out;
    float* out1 = out + NELEM;
    float* out2 = out + 2 * NELEM;
    float* out3 = out + 3 * NELEM;

    // small workspace: Ct (16384) | anc_kT (12800) | hist_k (12800) | flag
    float* ws      = (float*)d_ws;
    float* Ct      = ws;
    float* anc_kT  = ws + 16384;
    float* hist_k  = ws + 16384 + 12800;
    int*   flag    = (int*)(ws + 16384 + 25600);

    k1_prep<<<1, 256, 0, stream>>>(C_den, K_spk, tau_spk, dl_spk, tau_h, K_h, dl_h,
                                   Ct, anc_kT, hist_k, flag);
    // A -> out0, R -> out1
    k2_gemm<<<T_DATA / 16, 256, 0, stream>>>(Z_anc, Y_anc, Ct, out0, out1);
    // F -> out3 (reads A = out0)
    k3_conv<<<dim3(T_DATA / 40, 2), 256, 0, stream>>>(out0, anc_kT, out3);
    // final outputs (reads R = out1, F = out3; overwrites all four regions)
    k4_final<<<(NELEM / 4 + 255) / 256, 256, 0, stream>>>(S_conv, noise, W_sub, th_syn,
                                                          th_spk, W_spk, hist_k, flag,
                                                          out0, out1, out2, out3);
}